// Round 1
// baseline (1786.355 us; speedup 1.0000x reference)
//
#include <hip/hip_runtime.h>
#include <cstdint>
#include <cstddef>

// ---- problem constants ----
constexpr int G = 8;            // groups
constexpr int S = 1024;         // tokens per group
constexpr int E = 8;            // experts
constexpr int MD = 1024;        // model dim
constexpr int H = 5464;         // ffn dim
constexpr int HP = 5504;        // ffn dim padded to 43*128 (= 86*64)
constexpr int CAP = 256;        // capacity per (group, expert)
constexpr int T = G * S;        // 8192 tokens
constexpr int GC = G * CAP;     // 2048 rows per expert

typedef __bf16 bf16;
typedef __bf16 bf16x8 __attribute__((ext_vector_type(8)));
typedef __bf16 bf16x4 __attribute__((ext_vector_type(4)));
typedef float f32x4 __attribute__((ext_vector_type(4)));

__device__ __forceinline__ void async16(const void* g, void* l) {
    // global -> LDS direct DMA, 16B per lane; LDS dst = base + lane*16
    __builtin_amdgcn_global_load_lds((__attribute__((address_space(1))) void*)(g),
                                     (__attribute__((address_space(3))) void*)(l),
                                     16, 0, 0);
}

__device__ __forceinline__ float gelu_tanh(float x) {
    return 0.5f * x * (1.0f + tanhf(0.7978845608028654f * (x + 0.044715f * x * x * x)));
}

// swizzled element offset inside a [128 rows][64 k] bf16 LDS tile.
// granule = 8 bf16 (16B). LDS granule (row*8 + s) holds global k-granule (s ^ (row&7)).
__device__ __forceinline__ int sw_elem(int row, int gi) {
    return (row * 8 + (gi ^ (row & 7))) * 8;
}

// ---------------- router: logits + softmax + top2 (fp32, exact semantics) ----------------
__global__ void router_k(const float* __restrict__ x, const float* __restrict__ rw,
                         int* __restrict__ idx1, int* __restrict__ idx2,
                         float* __restrict__ gate1, float* __restrict__ gate2) {
    int wave = threadIdx.x >> 6, lane = threadIdx.x & 63;
    int t = blockIdx.x * 4 + wave;
    const float* xr = x + (size_t)t * MD;
    float acc[E];
#pragma unroll
    for (int e = 0; e < E; e++) acc[e] = 0.0f;
    for (int m = lane; m < MD; m += 64) {
        float xv = xr[m];
        const float* w = rw + m * E;
#pragma unroll
        for (int e = 0; e < E; e++) acc[e] += xv * w[e];
    }
#pragma unroll
    for (int off = 32; off > 0; off >>= 1) {
#pragma unroll
        for (int e = 0; e < E; e++) acc[e] += __shfl_xor(acc[e], off, 64);
    }
    if (lane == 0) {
        float mx = acc[0];
#pragma unroll
        for (int e = 1; e < E; e++) mx = fmaxf(mx, acc[e]);
        float raw[E]; float sum = 0.0f;
#pragma unroll
        for (int e = 0; e < E; e++) { raw[e] = expf(acc[e] - mx); sum += raw[e]; }
        float inv = 1.0f / sum;
#pragma unroll
        for (int e = 0; e < E; e++) raw[e] *= inv;
        // top-1: first max (jnp.argmax tie semantics)
        int i1 = 0; float b1 = raw[0];
#pragma unroll
        for (int e = 1; e < E; e++) if (raw[e] > b1) { b1 = raw[e]; i1 = e; }
        // top-2: argmax over rest (raw with idx1 zeroed), first-index ties
        int i2 = 0; float b2 = -1.0f;
#pragma unroll
        for (int e = 0; e < E; e++) {
            float v = (e == i1) ? 0.0f : raw[e];
            if (v > b2) { b2 = v; i2 = e; }
        }
        idx1[t] = i1; idx2[t] = i2; gate1[t] = b1; gate2[t] = b2;
    }
}

// ---------------- capacity scan: one wave per group, ballot prefix ----------------
__global__ void scan_k(const int* __restrict__ idx1, const int* __restrict__ idx2,
                       const float* __restrict__ gate1, const float* __restrict__ gate2,
                       int* __restrict__ tok1, int* __restrict__ tok2,
                       float* __restrict__ g1m, float* __restrict__ g2m,
                       int* __restrict__ slot_src, int* __restrict__ fill) {
    int g = blockIdx.x;
    int lane = threadIdx.x;
    unsigned long long lt = (1ull << lane) - 1ull;
    int cnt1[E], cnt2[E];
#pragma unroll
    for (int e = 0; e < E; e++) { cnt1[e] = 0; cnt2[e] = 0; }
    // pass 1: top-1 queue positions (exclusive cumsum of one-hot over S)
    for (int ch = 0; ch < S / 64; ch++) {
        int s = ch * 64 + lane, t = g * S + s;
        int i1 = idx1[t];
        int p = 0;
#pragma unroll
        for (int e = 0; e < E; e++) {
            unsigned long long m = __ballot(i1 == e);
            if (i1 == e) p = cnt1[e] + (int)__popcll(m & lt);
            cnt1[e] += (int)__popcll(m);
        }
        bool kept = p < CAP;
        tok1[t] = kept ? (i1 * CAP + p) : -1;
        g1m[t] = kept ? gate1[t] : 0.0f;
        if (kept) slot_src[((i1 * G + g) << 8) + p] = s;
    }
    int m1c[E];
#pragma unroll
    for (int e = 0; e < E; e++) m1c[e] = min(cnt1[e], CAP);
    // pass 2: top-2 queue, offset by kept top-1 count; raw cumsum (matches ref)
    for (int ch = 0; ch < S / 64; ch++) {
        int s = ch * 64 + lane, t = g * S + s;
        int i2 = idx2[t];
        float g2 = gate2[t];
        int p = 0;
#pragma unroll
        for (int e = 0; e < E; e++) {
            unsigned long long m = __ballot(i2 == e);
            if (i2 == e) p = m1c[e] + cnt2[e] + (int)__popcll(m & lt);
            cnt2[e] += (int)__popcll(m);
        }
        bool kept = p < CAP;
        bool nz = (g2 != 0.0f);
        tok2[t] = (kept && nz) ? (i2 * CAP + p) : -1;
        g2m[t] = (kept && nz) ? g2 : 0.0f;
        if (kept) slot_src[((i2 * G + g) << 8) + p] = nz ? s : -1;
    }
    if (lane < E) fill[lane * G + g] = min(m1c[lane] + cnt2[lane], CAP);
}

// ---------------- gather tokens into expert_in (bf16), zero unfilled slots ----------------
__global__ void gather_k(const float* __restrict__ x, const int* __restrict__ slot_src,
                         const int* __restrict__ fill, bf16* __restrict__ ein) {
    int slot = blockIdx.x;                       // (e*G+g)*CAP + c
    int c = slot & 255, g = (slot >> 8) & 7, e = slot >> 11;
    int i = threadIdx.x * 4;
    int src = (c < fill[e * G + g]) ? slot_src[slot] : -1;
    bf16x4 v;
    if (src >= 0) {
        float4 f = *(const float4*)(x + ((size_t)(g * S + src)) * MD + i);
        v[0] = (bf16)f.x; v[1] = (bf16)f.y; v[2] = (bf16)f.z; v[3] = (bf16)f.w;
    } else {
        v[0] = (bf16)0.0f; v[1] = (bf16)0.0f; v[2] = (bf16)0.0f; v[3] = (bf16)0.0f;
    }
    *(bf16x4*)(ein + (size_t)slot * MD + i) = v;
}

// ---------------- fp32 -> bf16 transpose with zero pad ----------------
// in:  (R x Cc) fp32 row-major, batch stride R*Cc
// out: (Cp x Rp) bf16 row-major, batch stride Cp*Rp; out[c][r] = (c<Cc && r<R) ? in[r][c] : 0
// grid: x = Cp/64, y = Rp/64, z = batch
__global__ void transpose_cast_k(const float* __restrict__ in, bf16* __restrict__ out,
                                 int R, int Cc, int Rp, int Cp) {
    __shared__ float lds[64][65];
    int c0 = blockIdx.x * 64;
    int r0 = blockIdx.y * 64;
    const float* bin = in + (size_t)blockIdx.z * R * Cc;
    bf16* bout = out + (size_t)blockIdx.z * Cp * Rp;
    int tid = threadIdx.x;
    int lr = tid >> 4;
    int lc = (tid & 15) * 4;
#pragma unroll
    for (int i = 0; i < 4; i++) {
        int r = r0 + lr + i * 16;
        float v0 = 0, v1 = 0, v2 = 0, v3 = 0;
        if (r < R) {
            const float* p = bin + (size_t)r * Cc + c0 + lc;
            if (c0 + lc + 3 < Cc) {
                float4 f = *(const float4*)p;
                v0 = f.x; v1 = f.y; v2 = f.z; v3 = f.w;
            } else {
                if (c0 + lc + 0 < Cc) v0 = p[0];
                if (c0 + lc + 1 < Cc) v1 = p[1];
                if (c0 + lc + 2 < Cc) v2 = p[2];
                if (c0 + lc + 3 < Cc) v3 = p[3];
            }
        }
        lds[lr + i * 16][lc + 0] = v0;
        lds[lr + i * 16][lc + 1] = v1;
        lds[lr + i * 16][lc + 2] = v2;
        lds[lr + i * 16][lc + 3] = v3;
    }
    __syncthreads();
    int orr = tid >> 2;            // out-row offset 0..63
    int oc = (tid & 3) * 16;       // out-col offset 0,16,32,48
    bf16x8 o0, o1;
#pragma unroll
    for (int j = 0; j < 8; j++) o0[j] = (bf16)lds[oc + j][orr];
#pragma unroll
    for (int j = 0; j < 8; j++) o1[j] = (bf16)lds[oc + 8 + j][orr];
    bf16* dst = bout + (size_t)(c0 + orr) * Rp + r0 + oc;
    *(bf16x8*)(dst) = o0;
    *(bf16x8*)(dst + 8) = o1;
}

// ---------------- GEMM1: ein @ {w0t,w1t}, fused GEGLU, write hidden bf16 ----------------
// grid: (GC/128 row tiles, HP/128 n tiles, E), block 256
__global__ __launch_bounds__(256) void gemm1_k(const bf16* __restrict__ ein,
                                               const bf16* __restrict__ w0t,
                                               const bf16* __restrict__ w1t,
                                               bf16* __restrict__ hidden) {
    int rt = blockIdx.x, nt = blockIdx.y, e = blockIdx.z;
    __shared__ __align__(16) bf16 As[128 * 64];
    __shared__ __align__(16) bf16 B0s[128 * 64];
    __shared__ __align__(16) bf16 B1s[128 * 64];
    int lane = threadIdx.x & 63, wave = threadIdx.x >> 6;
    int wm = wave & 1, wn = wave >> 1;
    const bf16* A  = ein + ((size_t)e * GC + rt * 128) * MD;
    const bf16* B0 = w0t + ((size_t)e * HP + nt * 128) * MD;
    const bf16* B1 = w1t + ((size_t)e * HP + nt * 128) * MD;
    f32x4 acc0[4][4], acc1[4][4];
    f32x4 z = {0.0f, 0.0f, 0.0f, 0.0f};
#pragma unroll
    for (int i = 0; i < 4; i++)
#pragma unroll
        for (int j = 0; j < 4; j++) { acc0[i][j] = z; acc1[i][j] = z; }
    int lr = lane >> 3, ls = lane & 7;
#pragma unroll 1
    for (int kt = 0; kt < MD / 64; kt++) {
        __syncthreads();
        int k0 = kt * 64;
#pragma unroll
        for (int i = 0; i < 4; i++) {
            int R0 = (i * 4 + wave) * 8;
            int r = R0 + lr;
            int gj = ls ^ (r & 7);
            size_t go = (size_t)r * MD + k0 + gj * 8;
            async16(A + go, &As[R0 * 64]);
            async16(B0 + go, &B0s[R0 * 64]);
            async16(B1 + go, &B1s[R0 * 64]);
        }
        __syncthreads();
#pragma unroll
        for (int ks = 0; ks < 2; ks++) {
            bf16x8 af[4], b0f[4], b1f[4];
            int gi = ks * 4 + (lane >> 4);
            int mrow = wm * 64 + (lane & 15);
            int nrow = wn * 64 + (lane & 15);
#pragma unroll
            for (int i = 0; i < 4; i++) {
                af[i]  = *(const bf16x8*)&As[sw_elem(mrow + i * 16, gi)];
                b0f[i] = *(const bf16x8*)&B0s[sw_elem(nrow + i * 16, gi)];
                b1f[i] = *(const bf16x8*)&B1s[sw_elem(nrow + i * 16, gi)];
            }
#pragma unroll
            for (int i = 0; i < 4; i++)
#pragma unroll
                for (int j = 0; j < 4; j++) {
                    acc0[i][j] = __builtin_amdgcn_mfma_f32_16x16x32_bf16(af[i], b0f[j], acc0[i][j], 0, 0, 0);
                    acc1[i][j] = __builtin_amdgcn_mfma_f32_16x16x32_bf16(af[i], b1f[j], acc1[i][j], 0, 0, 0);
                }
        }
    }
    // epilogue: hidden = gelu(h0) * h1, zero the HP pad columns
    bf16* Hb = hidden + (size_t)e * GC * HP;
    int colb = nt * 128 + wn * 64 + (lane & 15);
    int rowb = rt * 128 + wm * 64 + ((lane >> 4) * 4);
#pragma unroll
    for (int i = 0; i < 4; i++)
#pragma unroll
        for (int j = 0; j < 4; j++) {
            int col = colb + j * 16;
            bool ok = col < H;
#pragma unroll
            for (int r = 0; r < 4; r++) {
                int row = rowb + i * 16 + r;
                float v = ok ? gelu_tanh(acc0[i][j][r]) * acc1[i][j][r] : 0.0f;
                Hb[(size_t)row * HP + col] = (bf16)v;
            }
        }
}

// ---------------- GEMM2: hidden @ wot -> expert_out fp32 ----------------
// grid: (GC/128 row tiles, MD/128 n tiles, E), block 256
__global__ __launch_bounds__(256) void gemm2_k(const bf16* __restrict__ hidden,
                                               const bf16* __restrict__ wot,
                                               float* __restrict__ eout) {
    int rt = blockIdx.x, nt = blockIdx.y, e = blockIdx.z;
    __shared__ __align__(16) bf16 As[128 * 64];
    __shared__ __align__(16) bf16 Bs[128 * 64];
    int lane = threadIdx.x & 63, wave = threadIdx.x >> 6;
    int wm = wave & 1, wn = wave >> 1;
    const bf16* A = hidden + ((size_t)e * GC + rt * 128) * HP;
    const bf16* B = wot + ((size_t)e * MD + nt * 128) * HP;
    f32x4 acc[4][4];
    f32x4 z = {0.0f, 0.0f, 0.0f, 0.0f};
#pragma unroll
    for (int i = 0; i < 4; i++)
#pragma unroll
        for (int j = 0; j < 4; j++) acc[i][j] = z;
    int lr = lane >> 3, ls = lane & 7;
#pragma unroll 1
    for (int kt = 0; kt < HP / 64; kt++) {
        __syncthreads();
        int k0 = kt * 64;
#pragma unroll
        for (int i = 0; i < 4; i++) {
            int R0 = (i * 4 + wave) * 8;
            int r = R0 + lr;
            int gj = ls ^ (r & 7);
            size_t go = (size_t)r * HP + k0 + gj * 8;
            async16(A + go, &As[R0 * 64]);
            async16(B + go, &Bs[R0 * 64]);
        }
        __syncthreads();
#pragma unroll
        for (int ks = 0; ks < 2; ks++) {
            bf16x8 af[4], bf[4];
            int gi = ks * 4 + (lane >> 4);
            int mrow = wm * 64 + (lane & 15);
            int nrow = wn * 64 + (lane & 15);
#pragma unroll
            for (int i = 0; i < 4; i++) {
                af[i] = *(const bf16x8*)&As[sw_elem(mrow + i * 16, gi)];
                bf[i] = *(const bf16x8*)&Bs[sw_elem(nrow + i * 16, gi)];
            }
#pragma unroll
            for (int i = 0; i < 4; i++)
#pragma unroll
                for (int j = 0; j < 4; j++)
                    acc[i][j] = __builtin_amdgcn_mfma_f32_16x16x32_bf16(af[i], bf[j], acc[i][j], 0, 0, 0);
        }
    }
    float* Ob = eout + (size_t)e * GC * MD;
    int colb = nt * 128 + wn * 64 + (lane & 15);
    int rowb = rt * 128 + wm * 64 + ((lane >> 4) * 4);
#pragma unroll
    for (int i = 0; i < 4; i++)
#pragma unroll
        for (int j = 0; j < 4; j++) {
            int col = colb + j * 16;
#pragma unroll
            for (int r = 0; r < 4; r++) {
                int row = rowb + i * 16 + r;
                Ob[(size_t)row * MD + col] = acc[i][j][r];
            }
        }
}

// ---------------- combine: out[t] = g1*eout[slot1] + g2*eout[slot2] ----------------
__global__ void combine_k(const float* __restrict__ eout, const int* __restrict__ tok1,
                          const int* __restrict__ tok2, const float* __restrict__ g1m,
                          const float* __restrict__ g2m, float* __restrict__ out) {
    int t = blockIdx.x;
    int g = t >> 10;
    int i = threadIdx.x * 4;
    int r1 = tok1[t], r2 = tok2[t];
    float f1 = g1m[t], f2 = g2m[t];
    float4 o = {0, 0, 0, 0};
    if (r1 >= 0) {
        size_t row = (size_t)(((r1 >> 8) * G + g) * CAP + (r1 & 255));
        float4 v = *(const float4*)(eout + row * MD + i);
        o.x += f1 * v.x; o.y += f1 * v.y; o.z += f1 * v.z; o.w += f1 * v.w;
    }
    if (r2 >= 0) {
        size_t row = (size_t)(((r2 >> 8) * G + g) * CAP + (r2 & 255));
        float4 v = *(const float4*)(eout + row * MD + i);
        o.x += f2 * v.x; o.y += f2 * v.y; o.z += f2 * v.z; o.w += f2 * v.w;
    }
    *(float4*)(out + (size_t)t * MD + i) = o;
}

// ---------------- workspace layout ----------------
constexpr size_t SZ_TI = (size_t)T * 4;
constexpr size_t OFF_IDX1 = 0;
constexpr size_t OFF_IDX2 = OFF_IDX1 + SZ_TI;
constexpr size_t OFF_GT1  = OFF_IDX2 + SZ_TI;
constexpr size_t OFF_GT2  = OFF_GT1 + SZ_TI;
constexpr size_t OFF_G1M  = OFF_GT2 + SZ_TI;
constexpr size_t OFF_G2M  = OFF_G1M + SZ_TI;
constexpr size_t OFF_TK1  = OFF_G2M + SZ_TI;
constexpr size_t OFF_TK2  = OFF_TK1 + SZ_TI;
constexpr size_t OFF_SLOT = OFF_TK2 + SZ_TI;
constexpr size_t OFF_FILL = OFF_SLOT + (size_t)E * G * CAP * 4;
constexpr size_t OFF_EIN  = (OFF_FILL + (size_t)E * G * 4 + 255) & ~(size_t)255;
constexpr size_t OFF_W0T  = OFF_EIN + (size_t)E * GC * MD * 2;
constexpr size_t OFF_W1T  = OFF_W0T + (size_t)E * HP * MD * 2;
constexpr size_t OFF_WOT  = OFF_W1T + (size_t)E * HP * MD * 2;
constexpr size_t OFF_HID  = OFF_WOT + (size_t)E * MD * HP * 2;
constexpr size_t OFF_EOUT = OFF_HID + (size_t)E * GC * HP * 2;
// total ~552 MB

extern "C" void kernel_launch(void* const* d_in, const int* in_sizes, int n_in,
                              void* d_out, int out_size, void* d_ws, size_t ws_size,
                              hipStream_t stream) {
    const float* x  = (const float*)d_in[0];
    const float* rw = (const float*)d_in[1];
    const float* w0 = (const float*)d_in[2];
    const float* w1 = (const float*)d_in[3];
    const float* wo = (const float*)d_in[4];
    float* out = (float*)d_out;
    char* ws = (char*)d_ws;

    int*   idx1 = (int*)(ws + OFF_IDX1);
    int*   idx2 = (int*)(ws + OFF_IDX2);
    float* gt1  = (float*)(ws + OFF_GT1);
    float* gt2  = (float*)(ws + OFF_GT2);
    float* g1m  = (float*)(ws + OFF_G1M);
    float* g2m  = (float*)(ws + OFF_G2M);
    int*   tk1  = (int*)(ws + OFF_TK1);
    int*   tk2  = (int*)(ws + OFF_TK2);
    int*   slot = (int*)(ws + OFF_SLOT);
    int*   fill = (int*)(ws + OFF_FILL);
    bf16*  ein  = (bf16*)(ws + OFF_EIN);
    bf16*  w0t  = (bf16*)(ws + OFF_W0T);
    bf16*  w1t  = (bf16*)(ws + OFF_W1T);
    bf16*  wot  = (bf16*)(ws + OFF_WOT);
    bf16*  hid  = (bf16*)(ws + OFF_HID);
    float* eout = (float*)(ws + OFF_EOUT);

    router_k<<<T / 4, 256, 0, stream>>>(x, rw, idx1, idx2, gt1, gt2);
    scan_k<<<G, 64, 0, stream>>>(idx1, idx2, gt1, gt2, tk1, tk2, g1m, g2m, slot, fill);
    gather_k<<<E * G * CAP, 256, 0, stream>>>(x, slot, fill, ein);
    // weight pre-pass: fp32 -> bf16, transposed to K-contiguous, zero-padded
    transpose_cast_k<<<dim3(HP / 64, MD / 64, E), 256, 0, stream>>>(w0, w0t, MD, H, MD, HP);
    transpose_cast_k<<<dim3(HP / 64, MD / 64, E), 256, 0, stream>>>(w1, w1t, MD, H, MD, HP);
    transpose_cast_k<<<dim3(MD / 64, HP / 64, E), 256, 0, stream>>>(wo, wot, H, MD, HP, MD);
    gemm1_k<<<dim3(GC / 128, HP / 128, E), 256, 0, stream>>>(ein, w0t, w1t, hid);
    gemm2_k<<<dim3(GC / 128, MD / 128, E), 256, 0, stream>>>(hid, wot, eout);
    combine_k<<<T, 256, 0, stream>>>(eout, tk1, tk2, g1m, g2m, out);
}

// Round 2
// 1222.229 us; speedup vs baseline: 1.4616x; 1.4616x over previous
//
#include <hip/hip_runtime.h>
#include <cstdint>
#include <cstddef>

// ---- problem constants ----
constexpr int G = 8;            // groups
constexpr int S = 1024;         // tokens per group
constexpr int E = 8;            // experts
constexpr int MD = 1024;        // model dim
constexpr int H = 5464;         // ffn dim
constexpr int HP = 5504;        // ffn dim padded to 43*128 (= 86*64)
constexpr int CAP = 256;        // capacity per (group, expert)
constexpr int T = G * S;        // 8192 tokens
constexpr int GC = G * CAP;     // 2048 rows per expert

typedef __bf16 bf16;
typedef __bf16 bf16x8 __attribute__((ext_vector_type(8)));
typedef __bf16 bf16x4 __attribute__((ext_vector_type(4)));
typedef float f32x4 __attribute__((ext_vector_type(4)));

__device__ __forceinline__ void async16(const void* g, void* l) {
    // global -> LDS direct DMA, 16B per lane; LDS dst = base + lane*16
    __builtin_amdgcn_global_load_lds((__attribute__((address_space(1))) void*)(g),
                                     (__attribute__((address_space(3))) void*)(l),
                                     16, 0, 0);
}

__device__ __forceinline__ float gelu_tanh(float x) {
    return 0.5f * x * (1.0f + tanhf(0.7978845608028654f * (x + 0.044715f * x * x * x)));
}

// swizzled element offset inside a [rows][64 k] bf16 LDS tile.
// granule = 8 bf16 (16B). LDS granule (row*8 + s) holds global k-granule (s ^ (row&7)).
__device__ __forceinline__ int sw_elem(int row, int gi) {
    return (row * 8 + (gi ^ (row & 7))) * 8;
}

// ---------------- router: logits + softmax + top2 (fp32, exact semantics) ----------------
__global__ void router_k(const float* __restrict__ x, const float* __restrict__ rw,
                         int* __restrict__ idx1, int* __restrict__ idx2,
                         float* __restrict__ gate1, float* __restrict__ gate2) {
    int wave = threadIdx.x >> 6, lane = threadIdx.x & 63;
    int t = blockIdx.x * 4 + wave;
    const float* xr = x + (size_t)t * MD;
    float acc[E];
#pragma unroll
    for (int e = 0; e < E; e++) acc[e] = 0.0f;
    for (int m = lane; m < MD; m += 64) {
        float xv = xr[m];
        const float* w = rw + m * E;
#pragma unroll
        for (int e = 0; e < E; e++) acc[e] += xv * w[e];
    }
#pragma unroll
    for (int off = 32; off > 0; off >>= 1) {
#pragma unroll
        for (int e = 0; e < E; e++) acc[e] += __shfl_xor(acc[e], off, 64);
    }
    if (lane == 0) {
        float mx = acc[0];
#pragma unroll
        for (int e = 1; e < E; e++) mx = fmaxf(mx, acc[e]);
        float raw[E]; float sum = 0.0f;
#pragma unroll
        for (int e = 0; e < E; e++) { raw[e] = expf(acc[e] - mx); sum += raw[e]; }
        float inv = 1.0f / sum;
#pragma unroll
        for (int e = 0; e < E; e++) raw[e] *= inv;
        // top-1: first max (jnp.argmax tie semantics)
        int i1 = 0; float b1 = raw[0];
#pragma unroll
        for (int e = 1; e < E; e++) if (raw[e] > b1) { b1 = raw[e]; i1 = e; }
        // top-2: argmax over rest (raw with idx1 zeroed), first-index ties
        int i2 = 0; float b2 = -1.0f;
#pragma unroll
        for (int e = 0; e < E; e++) {
            float v = (e == i1) ? 0.0f : raw[e];
            if (v > b2) { b2 = v; i2 = e; }
        }
        idx1[t] = i1; idx2[t] = i2; gate1[t] = b1; gate2[t] = b2;
    }
}

// ---------------- capacity scan: one wave per group, ballot prefix ----------------
__global__ void scan_k(const int* __restrict__ idx1, const int* __restrict__ idx2,
                       const float* __restrict__ gate1, const float* __restrict__ gate2,
                       int* __restrict__ tok1, int* __restrict__ tok2,
                       float* __restrict__ g1m, float* __restrict__ g2m,
                       int* __restrict__ slot_src, int* __restrict__ fill) {
    int g = blockIdx.x;
    int lane = threadIdx.x;
    unsigned long long lt = (1ull << lane) - 1ull;
    int cnt1[E], cnt2[E];
#pragma unroll
    for (int e = 0; e < E; e++) { cnt1[e] = 0; cnt2[e] = 0; }
    // pass 1: top-1 queue positions (exclusive cumsum of one-hot over S)
    for (int ch = 0; ch < S / 64; ch++) {
        int s = ch * 64 + lane, t = g * S + s;
        int i1 = idx1[t];
        int p = 0;
#pragma unroll
        for (int e = 0; e < E; e++) {
            unsigned long long m = __ballot(i1 == e);
            if (i1 == e) p = cnt1[e] + (int)__popcll(m & lt);
            cnt1[e] += (int)__popcll(m);
        }
        bool kept = p < CAP;
        tok1[t] = kept ? (i1 * CAP + p) : -1;
        g1m[t] = kept ? gate1[t] : 0.0f;
        if (kept) slot_src[((i1 * G + g) << 8) + p] = s;
    }
    int m1c[E];
#pragma unroll
    for (int e = 0; e < E; e++) m1c[e] = min(cnt1[e], CAP);
    // pass 2: top-2 queue, offset by kept top-1 count; raw cumsum (matches ref)
    for (int ch = 0; ch < S / 64; ch++) {
        int s = ch * 64 + lane, t = g * S + s;
        int i2 = idx2[t];
        float g2 = gate2[t];
        int p = 0;
#pragma unroll
        for (int e = 0; e < E; e++) {
            unsigned long long m = __ballot(i2 == e);
            if (i2 == e) p = m1c[e] + cnt2[e] + (int)__popcll(m & lt);
            cnt2[e] += (int)__popcll(m);
        }
        bool kept = p < CAP;
        bool nz = (g2 != 0.0f);
        tok2[t] = (kept && nz) ? (i2 * CAP + p) : -1;
        g2m[t] = (kept && nz) ? g2 : 0.0f;
        if (kept) slot_src[((i2 * G + g) << 8) + p] = nz ? s : -1;
    }
    if (lane < E) fill[lane * G + g] = min(m1c[lane] + cnt2[lane], CAP);
}

// ---------------- gather tokens into expert_in (bf16), zero unfilled slots ----------------
__global__ void gather_k(const float* __restrict__ x, const int* __restrict__ slot_src,
                         const int* __restrict__ fill, bf16* __restrict__ ein) {
    int slot = blockIdx.x;                       // (e*G+g)*CAP + c
    int c = slot & 255, g = (slot >> 8) & 7, e = slot >> 11;
    int i = threadIdx.x * 4;
    int src = (c < fill[e * G + g]) ? slot_src[slot] : -1;
    bf16x4 v;
    if (src >= 0) {
        float4 f = *(const float4*)(x + ((size_t)(g * S + src)) * MD + i);
        v[0] = (bf16)f.x; v[1] = (bf16)f.y; v[2] = (bf16)f.z; v[3] = (bf16)f.w;
    } else {
        v[0] = (bf16)0.0f; v[1] = (bf16)0.0f; v[2] = (bf16)0.0f; v[3] = (bf16)0.0f;
    }
    *(bf16x4*)(ein + (size_t)slot * MD + i) = v;
}

// ---------------- fp32 -> bf16 transpose with zero pad ----------------
// in:  (R x Cc) fp32 row-major, batch stride R*Cc
// out: (Cp x Rp) bf16 row-major, batch stride Cp*Rp; out[c][r] = (c<Cc && r<R) ? in[r][c] : 0
// grid: x = Cp/64, y = Rp/64, z = batch
__global__ void transpose_cast_k(const float* __restrict__ in, bf16* __restrict__ out,
                                 int R, int Cc, int Rp, int Cp) {
    __shared__ float lds[64][65];
    int c0 = blockIdx.x * 64;
    int r0 = blockIdx.y * 64;
    const float* bin = in + (size_t)blockIdx.z * R * Cc;
    bf16* bout = out + (size_t)blockIdx.z * Cp * Rp;
    int tid = threadIdx.x;
    int lr = tid >> 4;
    int lc = (tid & 15) * 4;
#pragma unroll
    for (int i = 0; i < 4; i++) {
        int r = r0 + lr + i * 16;
        float v0 = 0, v1 = 0, v2 = 0, v3 = 0;
        if (r < R) {
            const float* p = bin + (size_t)r * Cc + c0 + lc;
            if (c0 + lc + 3 < Cc) {
                float4 f = *(const float4*)p;
                v0 = f.x; v1 = f.y; v2 = f.z; v3 = f.w;
            } else {
                if (c0 + lc + 0 < Cc) v0 = p[0];
                if (c0 + lc + 1 < Cc) v1 = p[1];
                if (c0 + lc + 2 < Cc) v2 = p[2];
                if (c0 + lc + 3 < Cc) v3 = p[3];
            }
        }
        lds[lr + i * 16][lc + 0] = v0;
        lds[lr + i * 16][lc + 1] = v1;
        lds[lr + i * 16][lc + 2] = v2;
        lds[lr + i * 16][lc + 3] = v3;
    }
    __syncthreads();
    int orr = tid >> 2;            // out-row offset 0..63
    int oc = (tid & 3) * 16;       // out-col offset 0,16,32,48
    bf16x8 o0, o1;
#pragma unroll
    for (int j = 0; j < 8; j++) o0[j] = (bf16)lds[oc + j][orr];
#pragma unroll
    for (int j = 0; j < 8; j++) o1[j] = (bf16)lds[oc + 8 + j][orr];
    bf16* dst = bout + (size_t)(c0 + orr) * Rp + r0 + oc;
    *(bf16x8*)(dst) = o0;
    *(bf16x8*)(dst + 8) = o1;
}

// ---------------- GEMM1: ein @ {w0t,w1t}, fused GEGLU, write hidden bf16 ----------------
// Block tile M=128 x N=64 (dual-B), wave tile 64x32 per matrix -> 64 AGPR acc.
// __launch_bounds__(256,3): cap regs at ~170 total -> 3 waves/SIMD.
// grid: (GC/128 row tiles, HP/64 n tiles, E), block 256
__global__ __launch_bounds__(256, 3) void gemm1_k(const bf16* __restrict__ ein,
                                                  const bf16* __restrict__ w0t,
                                                  const bf16* __restrict__ w1t,
                                                  bf16* __restrict__ hidden) {
    int rt = blockIdx.x, nt = blockIdx.y, e = blockIdx.z;
    __shared__ __align__(16) bf16 As[128 * 64];   // 16 KB
    __shared__ __align__(16) bf16 B0s[64 * 64];   // 8 KB
    __shared__ __align__(16) bf16 B1s[64 * 64];   // 8 KB
    int lane = threadIdx.x & 63, wave = threadIdx.x >> 6;
    int wm = wave & 1, wn = wave >> 1;            // wm: 64-row half; wn: 32-col half
    const bf16* A  = ein + ((size_t)e * GC + rt * 128) * MD;
    const bf16* B0 = w0t + ((size_t)e * HP + nt * 64) * MD;
    const bf16* B1 = w1t + ((size_t)e * HP + nt * 64) * MD;
    f32x4 acc0[4][2], acc1[4][2];                 // 16 x f32x4 = 64 AGPR
    f32x4 z = {0.0f, 0.0f, 0.0f, 0.0f};
#pragma unroll
    for (int i = 0; i < 4; i++)
#pragma unroll
        for (int j = 0; j < 2; j++) { acc0[i][j] = z; acc1[i][j] = z; }
    int lr = lane >> 3, ls = lane & 7;
#pragma unroll 1
    for (int kt = 0; kt < MD / 64; kt++) {
        __syncthreads();
        int k0 = kt * 64;
        // A: 16 chunks of 8 rows (4 per wave)
#pragma unroll
        for (int i = 0; i < 4; i++) {
            int c = i * 4 + wave;
            int r = c * 8 + lr;
            int gj = ls ^ (r & 7);
            async16(A + (size_t)r * MD + k0 + gj * 8, &As[c * 512]);
        }
        // B0/B1: 8 chunks of 8 rows each (2 per wave per matrix)
#pragma unroll
        for (int i = 0; i < 2; i++) {
            int c = i * 4 + wave;
            int r = c * 8 + lr;
            int gj = ls ^ (r & 7);
            size_t go = (size_t)r * MD + k0 + gj * 8;
            async16(B0 + go, &B0s[c * 512]);
            async16(B1 + go, &B1s[c * 512]);
        }
        __syncthreads();
#pragma unroll
        for (int ks = 0; ks < 2; ks++) {
            bf16x8 af[4], b0f[2], b1f[2];
            int gi = ks * 4 + (lane >> 4);
            int mrow = wm * 64 + (lane & 15);
            int nrow = wn * 32 + (lane & 15);
#pragma unroll
            for (int i = 0; i < 4; i++) af[i] = *(const bf16x8*)&As[sw_elem(mrow + i * 16, gi)];
#pragma unroll
            for (int j = 0; j < 2; j++) {
                b0f[j] = *(const bf16x8*)&B0s[sw_elem(nrow + j * 16, gi)];
                b1f[j] = *(const bf16x8*)&B1s[sw_elem(nrow + j * 16, gi)];
            }
#pragma unroll
            for (int i = 0; i < 4; i++)
#pragma unroll
                for (int j = 0; j < 2; j++) {
                    acc0[i][j] = __builtin_amdgcn_mfma_f32_16x16x32_bf16(af[i], b0f[j], acc0[i][j], 0, 0, 0);
                    acc1[i][j] = __builtin_amdgcn_mfma_f32_16x16x32_bf16(af[i], b1f[j], acc1[i][j], 0, 0, 0);
                }
        }
    }
    // epilogue: hidden = gelu(h0) * h1, zero the HP pad columns
    bf16* Hb = hidden + (size_t)e * GC * HP;
    int colb = nt * 64 + wn * 32 + (lane & 15);
    int rowb = rt * 128 + wm * 64 + ((lane >> 4) * 4);
#pragma unroll
    for (int i = 0; i < 4; i++)
#pragma unroll
        for (int j = 0; j < 2; j++) {
            int col = colb + j * 16;
            bool ok = col < H;
#pragma unroll
            for (int r = 0; r < 4; r++) {
                int row = rowb + i * 16 + r;
                float v = ok ? gelu_tanh(acc0[i][j][r]) * acc1[i][j][r] : 0.0f;
                Hb[(size_t)row * HP + col] = (bf16)v;
            }
        }
}

// ---------------- GEMM2: hidden @ wot -> expert_out fp32 ----------------
// grid: (GC/128 row tiles, MD/128 n tiles, E), block 256
__global__ __launch_bounds__(256) void gemm2_k(const bf16* __restrict__ hidden,
                                               const bf16* __restrict__ wot,
                                               float* __restrict__ eout) {
    int rt = blockIdx.x, nt = blockIdx.y, e = blockIdx.z;
    __shared__ __align__(16) bf16 As[128 * 64];
    __shared__ __align__(16) bf16 Bs[128 * 64];
    int lane = threadIdx.x & 63, wave = threadIdx.x >> 6;
    int wm = wave & 1, wn = wave >> 1;
    const bf16* A = hidden + ((size_t)e * GC + rt * 128) * HP;
    const bf16* B = wot + ((size_t)e * MD + nt * 128) * HP;
    f32x4 acc[4][4];
    f32x4 z = {0.0f, 0.0f, 0.0f, 0.0f};
#pragma unroll
    for (int i = 0; i < 4; i++)
#pragma unroll
        for (int j = 0; j < 4; j++) acc[i][j] = z;
    int lr = lane >> 3, ls = lane & 7;
#pragma unroll 1
    for (int kt = 0; kt < HP / 64; kt++) {
        __syncthreads();
        int k0 = kt * 64;
#pragma unroll
        for (int i = 0; i < 4; i++) {
            int R0 = (i * 4 + wave) * 8;
            int r = R0 + lr;
            int gj = ls ^ (r & 7);
            size_t go = (size_t)r * HP + k0 + gj * 8;
            async16(A + go, &As[R0 * 64]);
            async16(B + go, &Bs[R0 * 64]);
        }
        __syncthreads();
#pragma unroll
        for (int ks = 0; ks < 2; ks++) {
            bf16x8 af[4], bf[4];
            int gi = ks * 4 + (lane >> 4);
            int mrow = wm * 64 + (lane & 15);
            int nrow = wn * 64 + (lane & 15);
#pragma unroll
            for (int i = 0; i < 4; i++) {
                af[i] = *(const bf16x8*)&As[sw_elem(mrow + i * 16, gi)];
                bf[i] = *(const bf16x8*)&Bs[sw_elem(nrow + i * 16, gi)];
            }
#pragma unroll
            for (int i = 0; i < 4; i++)
#pragma unroll
                for (int j = 0; j < 4; j++)
                    acc[i][j] = __builtin_amdgcn_mfma_f32_16x16x32_bf16(af[i], bf[j], acc[i][j], 0, 0, 0);
        }
    }
    float* Ob = eout + (size_t)e * GC * MD;
    int colb = nt * 128 + wn * 64 + (lane & 15);
    int rowb = rt * 128 + wm * 64 + ((lane >> 4) * 4);
#pragma unroll
    for (int i = 0; i < 4; i++)
#pragma unroll
        for (int j = 0; j < 4; j++) {
            int col = colb + j * 16;
#pragma unroll
            for (int r = 0; r < 4; r++) {
                int row = rowb + i * 16 + r;
                Ob[(size_t)row * MD + col] = acc[i][j][r];
            }
        }
}

// ---------------- combine: out[t] = g1*eout[slot1] + g2*eout[slot2] ----------------
__global__ void combine_k(const float* __restrict__ eout, const int* __restrict__ tok1,
                          const int* __restrict__ tok2, const float* __restrict__ g1m,
                          const float* __restrict__ g2m, float* __restrict__ out) {
    int t = blockIdx.x;
    int g = t >> 10;
    int i = threadIdx.x * 4;
    int r1 = tok1[t], r2 = tok2[t];
    float f1 = g1m[t], f2 = g2m[t];
    float4 o = {0, 0, 0, 0};
    if (r1 >= 0) {
        size_t row = (size_t)(((r1 >> 8) * G + g) * CAP + (r1 & 255));
        float4 v = *(const float4*)(eout + row * MD + i);
        o.x += f1 * v.x; o.y += f1 * v.y; o.z += f1 * v.z; o.w += f1 * v.w;
    }
    if (r2 >= 0) {
        size_t row = (size_t)(((r2 >> 8) * G + g) * CAP + (r2 & 255));
        float4 v = *(const float4*)(eout + row * MD + i);
        o.x += f2 * v.x; o.y += f2 * v.y; o.z += f2 * v.z; o.w += f2 * v.w;
    }
    *(float4*)(out + (size_t)t * MD + i) = o;
}

// ---------------- workspace layout ----------------
constexpr size_t SZ_TI = (size_t)T * 4;
constexpr size_t OFF_IDX1 = 0;
constexpr size_t OFF_IDX2 = OFF_IDX1 + SZ_TI;
constexpr size_t OFF_GT1  = OFF_IDX2 + SZ_TI;
constexpr size_t OFF_GT2  = OFF_GT1 + SZ_TI;
constexpr size_t OFF_G1M  = OFF_GT2 + SZ_TI;
constexpr size_t OFF_G2M  = OFF_G1M + SZ_TI;
constexpr size_t OFF_TK1  = OFF_G2M + SZ_TI;
constexpr size_t OFF_TK2  = OFF_TK1 + SZ_TI;
constexpr size_t OFF_SLOT = OFF_TK2 + SZ_TI;
constexpr size_t OFF_FILL = OFF_SLOT + (size_t)E * G * CAP * 4;
constexpr size_t OFF_EIN  = (OFF_FILL + (size_t)E * G * 4 + 255) & ~(size_t)255;
constexpr size_t OFF_W0T  = OFF_EIN + (size_t)E * GC * MD * 2;
constexpr size_t OFF_W1T  = OFF_W0T + (size_t)E * HP * MD * 2;
constexpr size_t OFF_WOT  = OFF_W1T + (size_t)E * HP * MD * 2;
constexpr size_t OFF_HID  = OFF_WOT + (size_t)E * MD * HP * 2;
constexpr size_t OFF_EOUT = OFF_HID + (size_t)E * GC * HP * 2;
// total ~552 MB

extern "C" void kernel_launch(void* const* d_in, const int* in_sizes, int n_in,
                              void* d_out, int out_size, void* d_ws, size_t ws_size,
                              hipStream_t stream) {
    const float* x  = (const float*)d_in[0];
    const float* rw = (const float*)d_in[1];
    const float* w0 = (const float*)d_in[2];
    const float* w1 = (const float*)d_in[3];
    const float* wo = (const float*)d_in[4];
    float* out = (float*)d_out;
    char* ws = (char*)d_ws;

    int*   idx1 = (int*)(ws + OFF_IDX1);
    int*   idx2 = (int*)(ws + OFF_IDX2);
    float* gt1  = (float*)(ws + OFF_GT1);
    float* gt2  = (float*)(ws + OFF_GT2);
    float* g1m  = (float*)(ws + OFF_G1M);
    float* g2m  = (float*)(ws + OFF_G2M);
    int*   tk1  = (int*)(ws + OFF_TK1);
    int*   tk2  = (int*)(ws + OFF_TK2);
    int*   slot = (int*)(ws + OFF_SLOT);
    int*   fill = (int*)(ws + OFF_FILL);
    bf16*  ein  = (bf16*)(ws + OFF_EIN);
    bf16*  w0t  = (bf16*)(ws + OFF_W0T);
    bf16*  w1t  = (bf16*)(ws + OFF_W1T);
    bf16*  wot  = (bf16*)(ws + OFF_WOT);
    bf16*  hid  = (bf16*)(ws + OFF_HID);
    float* eout = (float*)(ws + OFF_EOUT);

    router_k<<<T / 4, 256, 0, stream>>>(x, rw, idx1, idx2, gt1, gt2);
    scan_k<<<G, 64, 0, stream>>>(idx1, idx2, gt1, gt2, tk1, tk2, g1m, g2m, slot, fill);
    gather_k<<<E * G * CAP, 256, 0, stream>>>(x, slot, fill, ein);
    // weight pre-pass: fp32 -> bf16, transposed to K-contiguous, zero-padded
    transpose_cast_k<<<dim3(HP / 64, MD / 64, E), 256, 0, stream>>>(w0, w0t, MD, H, MD, HP);
    transpose_cast_k<<<dim3(HP / 64, MD / 64, E), 256, 0, stream>>>(w1, w1t, MD, H, MD, HP);
    transpose_cast_k<<<dim3(MD / 64, HP / 64, E), 256, 0, stream>>>(wo, wot, H, MD, HP, MD);
    gemm1_k<<<dim3(GC / 128, HP / 64, E), 256, 0, stream>>>(ein, w0t, w1t, hid);
    gemm2_k<<<dim3(GC / 128, MD / 128, E), 256, 0, stream>>>(hid, wot, eout);
    combine_k<<<T, 256, 0, stream>>>(eout, tk1, tk2, g1m, g2m, out);
}